// Round 13
// baseline (98.892 us; speedup 1.0000x reference)
//
#include <hip/hip_runtime.h>
#include <math.h>

#define NR   2048
#define XD   512
#define HID  300
#define BS   256
#define NPAD 320
#define KTOT 1024
#define GSTR 304          // row stride for GPB/P0a/P0b (float4-aligned)
#define KP   320          // padded k (80 k4-slots; slots 75..79 exact zeros)
#define NNEG 256          // negpos blocks (1 per CU)

typedef __attribute__((ext_vector_type(8))) short bf16x8;
typedef __attribute__((ext_vector_type(4))) float f32x4;

__device__ __forceinline__ float softplus_f(float x) {
    return fmaxf(x, 0.f) + log1pf(__expf(-fabsf(x)));
}
__device__ __forceinline__ unsigned short f2bf(float f) {
    unsigned int u = __float_as_uint(f);
    u += 0x7FFFu + ((u >> 16) & 1u);   // RNE
    return (unsigned short)(u >> 16);
}
__device__ __forceinline__ bf16x8 cvt8(const float4 f0, const float4 f1) {
    bf16x8 r;
    r[0] = (short)f2bf(f0.x); r[1] = (short)f2bf(f0.y);
    r[2] = (short)f2bf(f0.z); r[3] = (short)f2bf(f0.w);
    r[4] = (short)f2bf(f1.x); r[5] = (short)f2bf(f1.y);
    r[6] = (short)f2bf(f1.z); r[7] = (short)f2bf(f1.w);
    return r;
}

// W1 [1024][300] -> Wt [320][1024] bf16, zero-padded rows 300..319.
// 320 blocks x 256 threads. Also resets the ticket counter.
__global__ __launch_bounds__(256) void wconvert(
    const float* __restrict__ W1, unsigned short* __restrict__ Wt,
    unsigned int* __restrict__ counter)
{
    __shared__ unsigned short ts[16][72];
    const int t = blockIdx.x, tid = threadIdx.x;
    if (t == 0 && tid == 0) *counter = 0u;
    const int nt = t % 20, kt = t / 20;   // 20 n-tiles x 16 k-tiles
    const int n = nt * 16 + (tid & 15);
    const int kl = tid >> 4;
    #pragma unroll
    for (int j = 0; j < 4; ++j) {
        const int k = kt * 64 + kl * 4 + j;
        ts[tid & 15][kl * 4 + j] = f2bf((n < HID) ? W1[k * HID + n] : 0.f);
    }
    __syncthreads();
    const int nw = tid >> 4, kw = (tid & 15) * 4;
    ushort4 o;
    o.x = ts[nw][kw]; o.y = ts[nw][kw + 1]; o.z = ts[nw][kw + 2]; o.w = ts[nw][kw + 3];
    *(ushort4*)(Wt + (nt * 16 + nw) * KTOT + kt * 64 + kw) = o;
}

// One wave per block, 32x32 tile of 16x16x32 MFMAs, all jobs K=512.
// A is read as fp32 and converted to bf16 in-register (no A staging pass).
// job 0: LP4 = nl@W1l   job 1: GPB = ng@W1g + b1
// job 2: P0a = pl@W1l   job 3: P0b = pg@W1g
// job 0 writes ALL n<320 -> LP4 k4-slots 75..79 are exact zeros.
__global__ __launch_bounds__(64) void mfma_gemm(
    const float* __restrict__ nl, const float* __restrict__ ng,
    const float* __restrict__ pl, const float* __restrict__ pg,
    const unsigned short* __restrict__ Wt, const float* __restrict__ b1,
    float* __restrict__ LP4, float* __restrict__ GPB,
    float* __restrict__ P0a, float* __restrict__ P0b)
{
    const int job = blockIdx.z;
    const int m0 = blockIdx.x * 32, n0 = blockIdx.y * 32;
    const int lane = threadIdx.x;
    const int r = lane & 15, g = lane >> 4;

    const float* Af = (job == 0) ? nl : (job == 1) ? ng : (job == 2) ? pl : pg;
    const int wb = (job & 1) * XD;

    const float* a0p = Af + (size_t)(m0 + r) * XD + 8 * g;
    const float* a1p = a0p + 16 * XD;
    const unsigned short* b0p = Wt + (n0 + r) * KTOT + wb + 8 * g;
    const unsigned short* b1p = b0p + 16 * KTOT;

    f32x4 acc00 = {0,0,0,0}, acc01 = {0,0,0,0}, acc10 = {0,0,0,0}, acc11 = {0,0,0,0};

    #pragma unroll
    for (int k = 0; k < XD; k += 32) {
        const bf16x8 a0 = cvt8(*(const float4*)(a0p + k), *(const float4*)(a0p + k + 4));
        const bf16x8 a1 = cvt8(*(const float4*)(a1p + k), *(const float4*)(a1p + k + 4));
        const bf16x8 w0 = *(const bf16x8*)(b0p + k);
        const bf16x8 w1 = *(const bf16x8*)(b1p + k);
        acc00 = __builtin_amdgcn_mfma_f32_16x16x32_bf16(a0, w0, acc00, 0, 0, 0);
        acc01 = __builtin_amdgcn_mfma_f32_16x16x32_bf16(a0, w1, acc01, 0, 0, 0);
        acc10 = __builtin_amdgcn_mfma_f32_16x16x32_bf16(a1, w0, acc10, 0, 0, 0);
        acc11 = __builtin_amdgcn_mfma_f32_16x16x32_bf16(a1, w1, acc11, 0, 0, 0);
    }

    f32x4 accs[2][2] = {{acc00, acc01}, {acc10, acc11}};
    #pragma unroll
    for (int mi = 0; mi < 2; ++mi) {
        #pragma unroll
        for (int ni = 0; ni < 2; ++ni) {
            const int n = n0 + ni * 16 + r;
            const int mb = m0 + mi * 16 + 4 * g;
            const f32x4 v = accs[mi][ni];
            if (job == 0) {
                float* base = LP4 + ((size_t)(n >> 2) * NR + mb) * 4 + (n & 3);
                base[0] = v[0]; base[4] = v[1]; base[8] = v[2]; base[12] = v[3];
            } else if (n < HID) {
                const float bias = (job == 1) ? b1[n] : 0.f;
                float* out = (job == 1) ? GPB : ((job == 2) ? P0a : P0b);
                #pragma unroll
                for (int j = 0; j < 4; ++j)
                    out[(size_t)(mb + j) * GSTR + n] = v[j] + bias;
            }
        }
    }
}

// 256 blocks x 1024 threads (1 block/CU, 16 waves = 4/SIMD):
//  neg: unit = (chunk = bid>>5, 8 g-rows = (bid&31)*8). Waves = k-16ths
//       (kh = tid>>6, 5 k4-slots each, compile-time), lane lh = tid&63,
//       L=4 l-streams. Same LP/LDS traffic as R12, 2x wave parallelism.
//       w*relu(t) = w't + w'|t| (w'=w/2); k4-slots 75..79 contribute 0.
//  sC by waves 0..7 (g-row = kh); pos rows by waves 8..15 (row bid*8+kh-8).
//  Last block (ticket) does logs + final sum.
__global__ __launch_bounds__(1024, 4) void negpos(
    const float* __restrict__ LP4, const float* __restrict__ GPB,
    const float* __restrict__ P0a, const float* __restrict__ P0b,
    const float* __restrict__ b1, const float* __restrict__ W2,
    const float* __restrict__ b2,
    float* __restrict__ negE, float* __restrict__ posP,
    unsigned int* __restrict__ counter, float* __restrict__ out)
{
    __shared__ __align__(16) float w2s[KP];
    __shared__ __align__(16) float gbs[8][KP];        // 10 KB
    __shared__ __align__(16) float pacc[16][BS][8];   // 128 KB
    __shared__ float sC[8];
    __shared__ float red[4][8];
    __shared__ float redp[8];
    __shared__ float redf[16];
    __shared__ int sh_last;
    const int tid = threadIdx.x, bid = blockIdx.x;
    const int kh = tid >> 6, lh = tid & 63;
    const float b2v = b2[0];

    const int chunk = bid >> 5, g0 = (bid & 31) * 8;
    const float* gp = GPB + (size_t)(chunk * BS + g0) * GSTR;
    for (int idx = tid; idx < KP; idx += 1024) {
        const bool v = idx < HID;
        w2s[idx] = v ? 0.5f * W2[idx] : 0.f;
        #pragma unroll
        for (int g = 0; g < 8; ++g)
            gbs[g][idx] = v ? gp[g * GSTR + idx] : 0.f;
    }
    __syncthreads();

    if (kh < 8) {
        // sC[g] = sum_k w'_k gp[g][k]; wave kh handles g-row kh (padded zeros)
        float c = 0.f;
        #pragma unroll
        for (int h = 0; h < 2; ++h) {
            const int k4 = lh + 64 * h;
            if (k4 < 80) {
                const float4 g4 = *(const float4*)&gbs[kh][k4 * 4];
                const float4 w4 = *(const float4*)&w2s[k4 * 4];
                c += g4.x * w4.x + g4.y * w4.y + g4.z * w4.z + g4.w * w4.w;
            }
        }
        #pragma unroll
        for (int o = 32; o > 0; o >>= 1) c += __shfl_xor(c, o);
        if (lh == 0) sC[kh] = c;
    } else {
        // positive term: wave kh handles row bid*8 + (kh-8)
        const int row = bid * 8 + (kh - 8);
        const float4* ra = (const float4*)(P0a + (size_t)row * GSTR);
        const float4* rb = (const float4*)(P0b + (size_t)row * GSTR);
        float d = 0.f;
        #pragma unroll
        for (int h = 0; h < 2; ++h) {
            const int k4 = lh + 64 * h;
            if (k4 < 75) {
                const float4 aa = ra[k4], bb4 = rb[k4];
                const float4 bb = *(const float4*)(b1 + k4 * 4);
                const float4 wv = *(const float4*)(W2 + k4 * 4);
                d += fmaxf(aa.x + bb4.x + bb.x, 0.f) * wv.x
                   + fmaxf(aa.y + bb4.y + bb.y, 0.f) * wv.y
                   + fmaxf(aa.z + bb4.z + bb.z, 0.f) * wv.z
                   + fmaxf(aa.w + bb4.w + bb.w, 0.f) * wv.w;
            }
        }
        #pragma unroll
        for (int o = 32; o > 0; o >>= 1) d += __shfl_xor(d, o);
        if (lh == 0) redp[kh - 8] = softplus_f(d + b2v);
    }

    // main loop: 5 k4-slots per wave, compile-time trip count
    const int k4beg = 5 * kh;
    const float4* lpb = (const float4*)LP4 + (chunk * BS + lh);

    float acc[8][4];      // [gt][j]
    float q[4] = {0.f, 0.f, 0.f, 0.f};
    #pragma unroll
    for (int gt = 0; gt < 8; ++gt)
        #pragma unroll
        for (int j = 0; j < 4; ++j) acc[gt][j] = 0.f;

    #pragma unroll
    for (int i = 0; i < 5; ++i) {
        const int k4 = k4beg + i;
        float4 a[4];
        #pragma unroll
        for (int j = 0; j < 4; ++j)
            a[j] = lpb[(size_t)k4 * NR + 64 * j];
        const float4 w4 = *(const float4*)&w2s[k4 * 4];
        #pragma unroll
        for (int j = 0; j < 4; ++j) {
            q[j] = fmaf(w4.x, a[j].x, q[j]);
            q[j] = fmaf(w4.y, a[j].y, q[j]);
            q[j] = fmaf(w4.z, a[j].z, q[j]);
            q[j] = fmaf(w4.w, a[j].w, q[j]);
        }
        #pragma unroll
        for (int gt = 0; gt < 8; ++gt) {
            const float4 g4 = *(const float4*)&gbs[gt][k4 * 4];
            #pragma unroll
            for (int j = 0; j < 4; ++j) {
                acc[gt][j] = fmaf(fabsf(g4.x + a[j].x), w4.x, acc[gt][j]);
                acc[gt][j] = fmaf(fabsf(g4.y + a[j].y), w4.y, acc[gt][j]);
                acc[gt][j] = fmaf(fabsf(g4.z + a[j].z), w4.z, acc[gt][j]);
                acc[gt][j] = fmaf(fabsf(g4.w + a[j].w), w4.w, acc[gt][j]);
            }
        }
    }

    #pragma unroll
    for (int j = 0; j < 4; ++j) {
        *(float4*)&pacc[kh][lh + 64 * j][0] =
            make_float4(acc[0][j] + q[j], acc[1][j] + q[j],
                        acc[2][j] + q[j], acc[3][j] + q[j]);
        *(float4*)&pacc[kh][lh + 64 * j][4] =
            make_float4(acc[4][j] + q[j], acc[5][j] + q[j],
                        acc[6][j] + q[j], acc[7][j] + q[j]);
    }
    __syncthreads();   // pacc + sC + redp ready

    // combine: thread tid<256 = l; s[gt] = sC[gt] + sum_kh pacc[kh][l][gt]
    if (tid < 256) {
        float s[8];
        #pragma unroll
        for (int gt = 0; gt < 8; ++gt) s[gt] = sC[gt];
        #pragma unroll
        for (int k = 0; k < 16; ++k) {
            const float4 p0 = *(const float4*)&pacc[k][tid][0];
            const float4 p1 = *(const float4*)&pacc[k][tid][4];
            s[0] += p0.x; s[1] += p0.y; s[2] += p0.z; s[3] += p0.w;
            s[4] += p1.x; s[5] += p1.y; s[6] += p1.z; s[7] += p1.w;
        }
        const int wid = tid >> 6;
        #pragma unroll
        for (int gt = 0; gt < 8; ++gt) {
            float v = __expf(softplus_f(s[gt] + b2v));
            #pragma unroll
            for (int o = 32; o > 0; o >>= 1) v += __shfl_xor(v, o);
            if ((tid & 63) == 0) red[wid][gt] = v;
        }
    }
    __syncthreads();
    if (tid == 0) {
        #pragma unroll
        for (int gt = 0; gt < 8; ++gt)
            negE[bid * 8 + gt] = red[0][gt] + red[1][gt] + red[2][gt] + red[3][gt];
        posP[bid] = redp[0] + redp[1] + redp[2] + redp[3]
                  + redp[4] + redp[5] + redp[6] + redp[7];
        __threadfence();
        const unsigned t = atomicAdd(counter, 1u);
        sh_last = (t == NNEG - 1) ? 1 : 0;
    }
    __syncthreads();

    // ---- last-block finalize (device-scope ticket over 256 blocks) ----
    if (sh_last) {
        __threadfence();
        const volatile float* ne = (const volatile float*)negE;
        const volatile float* pp = (const volatile float*)posP;
        float v = __logf(ne[tid]) + __logf(ne[tid + 1024]);
        if (tid < NNEG) v -= pp[tid];
        #pragma unroll
        for (int o = 32; o > 0; o >>= 1) v += __shfl_xor(v, o);
        if (lh == 0) redf[kh] = v;
        __syncthreads();
        if (tid == 0) {
            float s = 0.f;
            #pragma unroll
            for (int k = 0; k < 16; ++k) s += redf[k];
            out[0] = s * (1.f / 2048.f);
        }
    }
}

extern "C" void kernel_launch(void* const* d_in, const int* in_sizes, int n_in,
                              void* d_out, int out_size, void* d_ws, size_t ws_size,
                              hipStream_t stream)
{
    const float* pl = (const float*)d_in[0];
    const float* pg = (const float*)d_in[1];
    const float* nl = (const float*)d_in[2];
    const float* ng = (const float*)d_in[3];
    const float* W1 = (const float*)d_in[4];
    const float* b1 = (const float*)d_in[5];
    const float* W2 = (const float*)d_in[6];
    const float* b2 = (const float*)d_in[7];

    char* ws = (char*)d_ws;
    unsigned short* Wt = (unsigned short*)(ws);                   // 640 KB
    float* LP4  = (float*)(ws + (1u << 20));                      // 2.62 MB
    float* GPB  = (float*)(ws + (5u << 20));                      // 2.49 MB
    float* P0a  = (float*)(ws + (8u << 20));                      // 2.49 MB
    float* P0b  = (float*)(ws + (11u << 20));                     // 2.49 MB
    float* negE = (float*)(ws + (14u << 20));                     // 2048 f
    float* posP = negE + 2048;                                    // 256 f
    unsigned int* counter = (unsigned int*)(ws + (14u << 20) + 65536);
    float* out  = (float*)d_out;

    hipLaunchKernelGGL(wconvert, dim3(320), dim3(256), 0, stream,
                       W1, Wt, counter);
    hipLaunchKernelGGL(mfma_gemm, dim3(NR / 32, NPAD / 32, 4), dim3(64), 0, stream,
                       nl, ng, pl, pg, Wt, b1, LP4, GPB, P0a, P0b);
    hipLaunchKernelGGL(negpos, dim3(NNEG), dim3(1024), 0, stream,
                       LP4, GPB, P0a, P0b, b1, W2, b2, negE, posP, counter, out);
}

// Round 14
// 70.692 us; speedup vs baseline: 1.3989x; 1.3989x over previous
//
#include <hip/hip_runtime.h>
#include <math.h>

#define NR   2048
#define XD   512
#define HID  300
#define BS   256
#define NPAD 320
#define KTOT 1024
#define GSTR 304          // row stride for GPB/P0a/P0b (float4-aligned)
#define KP   320          // padded k (80 k4-slots; slots 75..79 exact zeros)
#define NNEG 256          // negpos blocks (1 per CU)

typedef __attribute__((ext_vector_type(8))) short bf16x8;
typedef __attribute__((ext_vector_type(4))) float f32x4;

__device__ __forceinline__ float softplus_f(float x) {
    return fmaxf(x, 0.f) + log1pf(__expf(-fabsf(x)));
}
__device__ __forceinline__ unsigned short f2bf(float f) {
    unsigned int u = __float_as_uint(f);
    u += 0x7FFFu + ((u >> 16) & 1u);   // RNE
    return (unsigned short)(u >> 16);
}
__device__ __forceinline__ bf16x8 cvt8(const float4 f0, const float4 f1) {
    bf16x8 r;
    r[0] = (short)f2bf(f0.x); r[1] = (short)f2bf(f0.y);
    r[2] = (short)f2bf(f0.z); r[3] = (short)f2bf(f0.w);
    r[4] = (short)f2bf(f1.x); r[5] = (short)f2bf(f1.y);
    r[6] = (short)f2bf(f1.z); r[7] = (short)f2bf(f1.w);
    return r;
}

// W1 [1024][300] -> Wt [320][1024] bf16, zero-padded rows 300..319.
// 320 blocks x 256 threads. Also resets the ticket counter.
__global__ __launch_bounds__(256) void wconvert(
    const float* __restrict__ W1, unsigned short* __restrict__ Wt,
    unsigned int* __restrict__ counter)
{
    __shared__ unsigned short ts[16][72];
    const int t = blockIdx.x, tid = threadIdx.x;
    if (t == 0 && tid == 0) *counter = 0u;
    const int nt = t % 20, kt = t / 20;   // 20 n-tiles x 16 k-tiles
    const int n = nt * 16 + (tid & 15);
    const int kl = tid >> 4;
    #pragma unroll
    for (int j = 0; j < 4; ++j) {
        const int k = kt * 64 + kl * 4 + j;
        ts[tid & 15][kl * 4 + j] = f2bf((n < HID) ? W1[k * HID + n] : 0.f);
    }
    __syncthreads();
    const int nw = tid >> 4, kw = (tid & 15) * 4;
    ushort4 o;
    o.x = ts[nw][kw]; o.y = ts[nw][kw + 1]; o.z = ts[nw][kw + 2]; o.w = ts[nw][kw + 3];
    *(ushort4*)(Wt + (nt * 16 + nw) * KTOT + kt * 64 + kw) = o;
}

// One wave per block, 32x32 tile of 16x16x32 MFMAs, all jobs K=512.
// A is read as fp32 and converted to bf16 in-register (no A staging pass).
// job 0: LP4 = nl@W1l   job 1: GPB = ng@W1g + b1
// job 2: P0a = pl@W1l   job 3: P0b = pg@W1g
// job 0 writes ALL n<320 -> LP4 k4-slots 75..79 are exact zeros.
__global__ __launch_bounds__(64) void mfma_gemm(
    const float* __restrict__ nl, const float* __restrict__ ng,
    const float* __restrict__ pl, const float* __restrict__ pg,
    const unsigned short* __restrict__ Wt, const float* __restrict__ b1,
    float* __restrict__ LP4, float* __restrict__ GPB,
    float* __restrict__ P0a, float* __restrict__ P0b)
{
    const int job = blockIdx.z;
    const int m0 = blockIdx.x * 32, n0 = blockIdx.y * 32;
    const int lane = threadIdx.x;
    const int r = lane & 15, g = lane >> 4;

    const float* Af = (job == 0) ? nl : (job == 1) ? ng : (job == 2) ? pl : pg;
    const int wb = (job & 1) * XD;

    const float* a0p = Af + (size_t)(m0 + r) * XD + 8 * g;
    const float* a1p = a0p + 16 * XD;
    const unsigned short* b0p = Wt + (n0 + r) * KTOT + wb + 8 * g;
    const unsigned short* b1p = b0p + 16 * KTOT;

    f32x4 acc00 = {0,0,0,0}, acc01 = {0,0,0,0}, acc10 = {0,0,0,0}, acc11 = {0,0,0,0};

    #pragma unroll
    for (int k = 0; k < XD; k += 32) {
        const bf16x8 a0 = cvt8(*(const float4*)(a0p + k), *(const float4*)(a0p + k + 4));
        const bf16x8 a1 = cvt8(*(const float4*)(a1p + k), *(const float4*)(a1p + k + 4));
        const bf16x8 w0 = *(const bf16x8*)(b0p + k);
        const bf16x8 w1 = *(const bf16x8*)(b1p + k);
        acc00 = __builtin_amdgcn_mfma_f32_16x16x32_bf16(a0, w0, acc00, 0, 0, 0);
        acc01 = __builtin_amdgcn_mfma_f32_16x16x32_bf16(a0, w1, acc01, 0, 0, 0);
        acc10 = __builtin_amdgcn_mfma_f32_16x16x32_bf16(a1, w0, acc10, 0, 0, 0);
        acc11 = __builtin_amdgcn_mfma_f32_16x16x32_bf16(a1, w1, acc11, 0, 0, 0);
    }

    f32x4 accs[2][2] = {{acc00, acc01}, {acc10, acc11}};
    #pragma unroll
    for (int mi = 0; mi < 2; ++mi) {
        #pragma unroll
        for (int ni = 0; ni < 2; ++ni) {
            const int n = n0 + ni * 16 + r;
            const int mb = m0 + mi * 16 + 4 * g;
            const f32x4 v = accs[mi][ni];
            if (job == 0) {
                float* base = LP4 + ((size_t)(n >> 2) * NR + mb) * 4 + (n & 3);
                base[0] = v[0]; base[4] = v[1]; base[8] = v[2]; base[12] = v[3];
            } else if (n < HID) {
                const float bias = (job == 1) ? b1[n] : 0.f;
                float* out = (job == 1) ? GPB : ((job == 2) ? P0a : P0b);
                #pragma unroll
                for (int j = 0; j < 4; ++j)
                    out[(size_t)(mb + j) * GSTR + n] = v[j] + bias;
            }
        }
    }
}

// 256 blocks x 512 threads, 1 block/CU, XCD-swizzled:
//  chunk = bid & 7  -> all 32 blocks sharing a chunk's LP/GPB slab land on
//  the SAME XCD (bid%8 = XCD round-robin), so the slab is fetched from L3
//  once per XCD and re-reads hit the 4MB local L2.
//  g0 = (bid>>3)*8 g-rows. Waves = k-eighths (kh = tid>>6, 10 k4-slots,
//  compile-time), lane lh = tid&63, L=4 l-streams.
//  w*relu(t) = w't + w'|t| (w'=w/2); k4-slots 75..79 contribute 0.
//  pos rows: wave kh handles row bid*8+kh. Last block (ticket) finalizes.
__global__ __launch_bounds__(512, 2) void negpos(
    const float* __restrict__ LP4, const float* __restrict__ GPB,
    const float* __restrict__ P0a, const float* __restrict__ P0b,
    const float* __restrict__ b1, const float* __restrict__ W2,
    const float* __restrict__ b2,
    float* __restrict__ negE, float* __restrict__ posP,
    unsigned int* __restrict__ counter, float* __restrict__ out)
{
    __shared__ __align__(16) float w2s[KP];
    __shared__ __align__(16) float gbs[8][KP];        // 10 KB
    __shared__ __align__(16) float pacc[8][BS][8];    // 64 KB
    __shared__ float sC[8];
    __shared__ float red[4][8];
    __shared__ float redp[8];
    __shared__ int sh_last;
    const int tid = threadIdx.x, bid = blockIdx.x;
    const int kh = tid >> 6, lh = tid & 63;
    const float b2v = b2[0];

    const int chunk = bid & 7, g0 = (bid >> 3) * 8;   // XCD-local chunk slab
    const float* gp = GPB + (size_t)(chunk * BS + g0) * GSTR;
    for (int idx = tid; idx < KP; idx += 512) {
        const bool v = idx < HID;
        w2s[idx] = v ? 0.5f * W2[idx] : 0.f;
        #pragma unroll
        for (int g = 0; g < 8; ++g)
            gbs[g][idx] = v ? gp[g * GSTR + idx] : 0.f;
    }
    __syncthreads();

    // sC[g] = sum_k w'_k gp[g][k]; wave kh handles g-row kh (padded zeros)
    {
        float c = 0.f;
        #pragma unroll
        for (int h = 0; h < 2; ++h) {
            const int k4 = lh + 64 * h;
            if (k4 < 80) {
                const float4 g4 = *(const float4*)&gbs[kh][k4 * 4];
                const float4 w4 = *(const float4*)&w2s[k4 * 4];
                c += g4.x * w4.x + g4.y * w4.y + g4.z * w4.z + g4.w * w4.w;
            }
        }
        #pragma unroll
        for (int o = 32; o > 0; o >>= 1) c += __shfl_xor(c, o);
        if (lh == 0) sC[kh] = c;
    }

    // main loop: 10 k4-slots per wave, compile-time trip count
    const int k4beg = 10 * kh;
    const float4* lpb = (const float4*)LP4 + (chunk * BS + lh);

    float acc[8][4];      // [gt][j]
    float q[4] = {0.f, 0.f, 0.f, 0.f};
    #pragma unroll
    for (int gt = 0; gt < 8; ++gt)
        #pragma unroll
        for (int j = 0; j < 4; ++j) acc[gt][j] = 0.f;

    #pragma unroll
    for (int i = 0; i < 10; ++i) {
        const int k4 = k4beg + i;
        float4 a[4];
        #pragma unroll
        for (int j = 0; j < 4; ++j)
            a[j] = lpb[(size_t)k4 * NR + 64 * j];
        const float4 w4 = *(const float4*)&w2s[k4 * 4];
        #pragma unroll
        for (int j = 0; j < 4; ++j) {
            q[j] = fmaf(w4.x, a[j].x, q[j]);
            q[j] = fmaf(w4.y, a[j].y, q[j]);
            q[j] = fmaf(w4.z, a[j].z, q[j]);
            q[j] = fmaf(w4.w, a[j].w, q[j]);
        }
        #pragma unroll
        for (int gt = 0; gt < 8; ++gt) {
            const float4 g4 = *(const float4*)&gbs[gt][k4 * 4];
            #pragma unroll
            for (int j = 0; j < 4; ++j) {
                acc[gt][j] = fmaf(fabsf(g4.x + a[j].x), w4.x, acc[gt][j]);
                acc[gt][j] = fmaf(fabsf(g4.y + a[j].y), w4.y, acc[gt][j]);
                acc[gt][j] = fmaf(fabsf(g4.z + a[j].z), w4.z, acc[gt][j]);
                acc[gt][j] = fmaf(fabsf(g4.w + a[j].w), w4.w, acc[gt][j]);
            }
        }
    }

    #pragma unroll
    for (int j = 0; j < 4; ++j) {
        *(float4*)&pacc[kh][lh + 64 * j][0] =
            make_float4(acc[0][j] + q[j], acc[1][j] + q[j],
                        acc[2][j] + q[j], acc[3][j] + q[j]);
        *(float4*)&pacc[kh][lh + 64 * j][4] =
            make_float4(acc[4][j] + q[j], acc[5][j] + q[j],
                        acc[6][j] + q[j], acc[7][j] + q[j]);
    }
    __syncthreads();   // pacc + sC ready

    // combine: thread tid<256 = l; s[gt] = sC[gt] + sum_kh pacc[kh][l][gt]
    if (tid < 256) {
        float s[8];
        #pragma unroll
        for (int gt = 0; gt < 8; ++gt) s[gt] = sC[gt];
        #pragma unroll
        for (int k = 0; k < 8; ++k) {
            const float4 p0 = *(const float4*)&pacc[k][tid][0];
            const float4 p1 = *(const float4*)&pacc[k][tid][4];
            s[0] += p0.x; s[1] += p0.y; s[2] += p0.z; s[3] += p0.w;
            s[4] += p1.x; s[5] += p1.y; s[6] += p1.z; s[7] += p1.w;
        }
        const int wid = tid >> 6;
        #pragma unroll
        for (int gt = 0; gt < 8; ++gt) {
            float v = __expf(softplus_f(s[gt] + b2v));
            #pragma unroll
            for (int o = 32; o > 0; o >>= 1) v += __shfl_xor(v, o);
            if ((tid & 63) == 0) red[wid][gt] = v;
        }
    }
    __syncthreads();
    if (tid == 0) {
        #pragma unroll
        for (int gt = 0; gt < 8; ++gt)
            negE[(chunk * 32 + (bid >> 3)) * 8 + gt] =
                red[0][gt] + red[1][gt] + red[2][gt] + red[3][gt];
    }

    // ---- positive term: wave kh handles row bid*8 + kh ----
    {
        const int row = bid * 8 + kh;
        const float4* ra = (const float4*)(P0a + (size_t)row * GSTR);
        const float4* rb = (const float4*)(P0b + (size_t)row * GSTR);
        float d = 0.f;
        #pragma unroll
        for (int h = 0; h < 2; ++h) {
            const int k4 = lh + 64 * h;
            if (k4 < 75) {
                const float4 aa = ra[k4], bb4 = rb[k4];
                const float4 bb = *(const float4*)(b1 + k4 * 4);
                const float4 wv = *(const float4*)(W2 + k4 * 4);
                d += fmaxf(aa.x + bb4.x + bb.x, 0.f) * wv.x
                   + fmaxf(aa.y + bb4.y + bb.y, 0.f) * wv.y
                   + fmaxf(aa.z + bb4.z + bb.z, 0.f) * wv.z
                   + fmaxf(aa.w + bb4.w + bb.w, 0.f) * wv.w;
            }
        }
        #pragma unroll
        for (int o = 32; o > 0; o >>= 1) d += __shfl_xor(d, o);
        if (lh == 0) redp[kh] = softplus_f(d + b2v);
    }
    __syncthreads();

    // ---- last-block finalize (device-scope ticket over 256 blocks) ----
    if (tid == 0) {
        posP[bid] = redp[0] + redp[1] + redp[2] + redp[3]
                  + redp[4] + redp[5] + redp[6] + redp[7];
        __threadfence();
        const unsigned t = atomicAdd(counter, 1u);
        sh_last = (t == NNEG - 1) ? 1 : 0;
    }
    __syncthreads();
    if (sh_last) {
        __threadfence();
        const volatile float* ne = (const volatile float*)negE;
        const volatile float* pp = (const volatile float*)posP;
        float v = 0.f;
        for (int i = tid; i < 2048; i += 512)
            v += __logf(ne[i]);
        if (tid < NNEG) v -= pp[tid];
        #pragma unroll
        for (int o = 32; o > 0; o >>= 1) v += __shfl_xor(v, o);
        if (lh == 0) redp[kh] = v;
        __syncthreads();
        if (tid == 0)
            out[0] = (redp[0] + redp[1] + redp[2] + redp[3]
                    + redp[4] + redp[5] + redp[6] + redp[7]) * (1.f / 2048.f);
    }
}

extern "C" void kernel_launch(void* const* d_in, const int* in_sizes, int n_in,
                              void* d_out, int out_size, void* d_ws, size_t ws_size,
                              hipStream_t stream)
{
    const float* pl = (const float*)d_in[0];
    const float* pg = (const float*)d_in[1];
    const float* nl = (const float*)d_in[2];
    const float* ng = (const float*)d_in[3];
    const float* W1 = (const float*)d_in[4];
    const float* b1 = (const float*)d_in[5];
    const float* W2 = (const float*)d_in[6];
    const float* b2 = (const float*)d_in[7];

    char* ws = (char*)d_ws;
    unsigned short* Wt = (unsigned short*)(ws);                   // 640 KB
    float* LP4  = (float*)(ws + (1u << 20));                      // 2.62 MB
    float* GPB  = (float*)(ws + (5u << 20));                      // 2.49 MB
    float* P0a  = (float*)(ws + (8u << 20));                      // 2.49 MB
    float* P0b  = (float*)(ws + (11u << 20));                     // 2.49 MB
    float* negE = (float*)(ws + (14u << 20));                     // 2048 f
    float* posP = negE + 2048;                                    // 256 f
    unsigned int* counter = (unsigned int*)(ws + (14u << 20) + 65536);
    float* out  = (float*)d_out;

    hipLaunchKernelGGL(wconvert, dim3(320), dim3(256), 0, stream,
                       W1, Wt, counter);
    hipLaunchKernelGGL(mfma_gemm, dim3(NR / 32, NPAD / 32, 4), dim3(64), 0, stream,
                       nl, ng, pl, pg, Wt, b1, LP4, GPB, P0a, P0b);
    hipLaunchKernelGGL(negpos, dim3(NNEG), dim3(512), 0, stream,
                       LP4, GPB, P0a, P0b, b1, W2, b2, negE, posP, counter, out);
}

// Round 15
// 69.692 us; speedup vs baseline: 1.4190x; 1.0143x over previous
//
#include <hip/hip_runtime.h>
#include <math.h>

#define NR   2048
#define XD   512
#define HID  300
#define BS   256
#define NPAD 320
#define KTOT 1024
#define GSTR 304          // row stride for P0a/P0b (float4-aligned)
#define HSTR 304          // row stride for GPBh (ushort)
#define KP   320          // padded k (40 k8-slots; k>=300 exact zeros)
#define NNEG 256          // negpos blocks (1 per CU)

typedef __attribute__((ext_vector_type(8))) short bf16x8;
typedef __attribute__((ext_vector_type(8))) unsigned short u16x8;
typedef __attribute__((ext_vector_type(4))) float f32x4;

__device__ __forceinline__ float softplus_f(float x) {
    return fmaxf(x, 0.f) + log1pf(__expf(-fabsf(x)));
}
__device__ __forceinline__ unsigned short f2bf(float f) {
    unsigned int u = __float_as_uint(f);
    u += 0x7FFFu + ((u >> 16) & 1u);   // RNE
    return (unsigned short)(u >> 16);
}
__device__ __forceinline__ float bf2f(unsigned short h) {
    return __uint_as_float((unsigned int)h << 16);
}
__device__ __forceinline__ bf16x8 cvt8(const float4 f0, const float4 f1) {
    bf16x8 r;
    r[0] = (short)f2bf(f0.x); r[1] = (short)f2bf(f0.y);
    r[2] = (short)f2bf(f0.z); r[3] = (short)f2bf(f0.w);
    r[4] = (short)f2bf(f1.x); r[5] = (short)f2bf(f1.y);
    r[6] = (short)f2bf(f1.z); r[7] = (short)f2bf(f1.w);
    return r;
}

// W1 [1024][300] -> Wt [320][1024] bf16, zero-padded rows 300..319.
// 320 blocks x 256 threads. Also resets the ticket counter.
__global__ __launch_bounds__(256) void wconvert(
    const float* __restrict__ W1, unsigned short* __restrict__ Wt,
    unsigned int* __restrict__ counter)
{
    __shared__ unsigned short ts[16][72];
    const int t = blockIdx.x, tid = threadIdx.x;
    if (t == 0 && tid == 0) *counter = 0u;
    const int nt = t % 20, kt = t / 20;   // 20 n-tiles x 16 k-tiles
    const int n = nt * 16 + (tid & 15);
    const int kl = tid >> 4;
    #pragma unroll
    for (int j = 0; j < 4; ++j) {
        const int k = kt * 64 + kl * 4 + j;
        ts[tid & 15][kl * 4 + j] = f2bf((n < HID) ? W1[k * HID + n] : 0.f);
    }
    __syncthreads();
    const int nw = tid >> 4, kw = (tid & 15) * 4;
    ushort4 o;
    o.x = ts[nw][kw]; o.y = ts[nw][kw + 1]; o.z = ts[nw][kw + 2]; o.w = ts[nw][kw + 3];
    *(ushort4*)(Wt + (nt * 16 + nw) * KTOT + kt * 64 + kw) = o;
}

// One wave per block, 32x32 tile of 16x16x32 MFMAs, all jobs K=512.
// A read as fp32, converted to bf16 in-register.
// job 0: LP4h = nl@W1l  -> bf16 [k8 0..39][l 0..2047][8]   (k>=300 exact 0)
// job 1: GPBh = ng@W1g + b1 -> bf16 [row][HSTR]
// job 2: P0a = pl@W1l (f32)   job 3: P0b = pg@W1g (f32)
__global__ __launch_bounds__(64) void mfma_gemm(
    const float* __restrict__ nl, const float* __restrict__ ng,
    const float* __restrict__ pl, const float* __restrict__ pg,
    const unsigned short* __restrict__ Wt, const float* __restrict__ b1,
    unsigned short* __restrict__ LP4h, unsigned short* __restrict__ GPBh,
    float* __restrict__ P0a, float* __restrict__ P0b)
{
    const int job = blockIdx.z;
    const int m0 = blockIdx.x * 32, n0 = blockIdx.y * 32;
    const int lane = threadIdx.x;
    const int r = lane & 15, g = lane >> 4;

    const float* Af = (job == 0) ? nl : (job == 1) ? ng : (job == 2) ? pl : pg;
    const int wb = (job & 1) * XD;

    const float* a0p = Af + (size_t)(m0 + r) * XD + 8 * g;
    const float* a1p = a0p + 16 * XD;
    const unsigned short* b0p = Wt + (n0 + r) * KTOT + wb + 8 * g;
    const unsigned short* b1p = b0p + 16 * KTOT;

    f32x4 acc00 = {0,0,0,0}, acc01 = {0,0,0,0}, acc10 = {0,0,0,0}, acc11 = {0,0,0,0};

    #pragma unroll
    for (int k = 0; k < XD; k += 32) {
        const bf16x8 a0 = cvt8(*(const float4*)(a0p + k), *(const float4*)(a0p + k + 4));
        const bf16x8 a1 = cvt8(*(const float4*)(a1p + k), *(const float4*)(a1p + k + 4));
        const bf16x8 w0 = *(const bf16x8*)(b0p + k);
        const bf16x8 w1 = *(const bf16x8*)(b1p + k);
        acc00 = __builtin_amdgcn_mfma_f32_16x16x32_bf16(a0, w0, acc00, 0, 0, 0);
        acc01 = __builtin_amdgcn_mfma_f32_16x16x32_bf16(a0, w1, acc01, 0, 0, 0);
        acc10 = __builtin_amdgcn_mfma_f32_16x16x32_bf16(a1, w0, acc10, 0, 0, 0);
        acc11 = __builtin_amdgcn_mfma_f32_16x16x32_bf16(a1, w1, acc11, 0, 0, 0);
    }

    f32x4 accs[2][2] = {{acc00, acc01}, {acc10, acc11}};
    #pragma unroll
    for (int mi = 0; mi < 2; ++mi) {
        #pragma unroll
        for (int ni = 0; ni < 2; ++ni) {
            const int n = n0 + ni * 16 + r;     // k index (job 0) / col (others)
            const int mb = m0 + mi * 16 + 4 * g;
            const f32x4 v = accs[mi][ni];
            if (job == 0) {
                unsigned short* base = LP4h + ((size_t)(n >> 3) * NR + mb) * 8 + (n & 7);
                base[0]  = f2bf(v[0]); base[8]  = f2bf(v[1]);
                base[16] = f2bf(v[2]); base[24] = f2bf(v[3]);
            } else if (n < HID) {
                if (job == 1) {
                    const float bias = b1[n];
                    #pragma unroll
                    for (int j = 0; j < 4; ++j)
                        GPBh[(size_t)(mb + j) * HSTR + n] = f2bf(v[j] + bias);
                } else {
                    float* out = (job == 2) ? P0a : P0b;
                    #pragma unroll
                    for (int j = 0; j < 4; ++j)
                        out[(size_t)(mb + j) * GSTR + n] = v[j];
                }
            }
        }
    }
}

// 256 blocks x 512 threads, 1 block/CU equivalent occupancy 2/CU:
//  neg unit = (chunk = bid>>5, 8 g-rows = (bid&31)*8). Waves = k-eighths
//  (kh = tid>>6, 5 k8-slots each, compile-time), lane lh = tid&63,
//  L=4 l-streams. LP read from bf16 (total streaming set 2.5 MB -> L2-fits
//  on every XCD under any block placement).
//  w*relu(t) = w't + w'|t| (w'=w/2); k>=300 slots contribute exact 0.
//  pos rows: wave kh handles row bid*8+kh. Last block (ticket) finalizes.
__global__ __launch_bounds__(512, 2) void negpos(
    const unsigned short* __restrict__ LP4h, const unsigned short* __restrict__ GPBh,
    const float* __restrict__ P0a, const float* __restrict__ P0b,
    const float* __restrict__ b1, const float* __restrict__ W2,
    const float* __restrict__ b2,
    float* __restrict__ negE, float* __restrict__ posP,
    unsigned int* __restrict__ counter, float* __restrict__ out)
{
    __shared__ __align__(16) float w2s[KP];
    __shared__ __align__(16) float gbs[8][KP];        // 10 KB
    __shared__ __align__(16) float pacc[8][BS][8];    // 64 KB
    __shared__ float sC[8];
    __shared__ float red[4][8];
    __shared__ float redp[8];
    __shared__ int sh_last;
    const int tid = threadIdx.x, bid = blockIdx.x;
    const int kh = tid >> 6, lh = tid & 63;
    const float b2v = b2[0];

    const int chunk = bid >> 5, g0 = (bid & 31) * 8;
    const unsigned short* gp = GPBh + (size_t)(chunk * BS + g0) * HSTR;
    for (int idx = tid; idx < KP; idx += 512) {
        const bool v = idx < HID;
        w2s[idx] = v ? 0.5f * W2[idx] : 0.f;
        #pragma unroll
        for (int g = 0; g < 8; ++g)
            gbs[g][idx] = v ? bf2f(gp[g * HSTR + idx]) : 0.f;
    }
    __syncthreads();

    // sC[g] = sum_k w'_k gp[g][k]; wave kh handles g-row kh (padded zeros)
    {
        float c = 0.f;
        #pragma unroll
        for (int h = 0; h < 2; ++h) {
            const int k4 = lh + 64 * h;
            if (k4 < 80) {
                const float4 g4 = *(const float4*)&gbs[kh][k4 * 4];
                const float4 w4 = *(const float4*)&w2s[k4 * 4];
                c += g4.x * w4.x + g4.y * w4.y + g4.z * w4.z + g4.w * w4.w;
            }
        }
        #pragma unroll
        for (int o = 32; o > 0; o >>= 1) c += __shfl_xor(c, o);
        if (lh == 0) sC[kh] = c;
    }

    // main loop: 5 k8-slots per wave (40 total), compile-time trip count
    const int k8beg = 5 * kh;
    const unsigned short* lpb = LP4h + ((size_t)0 * NR + chunk * BS + lh) * 8;

    float acc[8][4];      // [gt][j]
    float q[4] = {0.f, 0.f, 0.f, 0.f};
    #pragma unroll
    for (int gt = 0; gt < 8; ++gt)
        #pragma unroll
        for (int j = 0; j < 4; ++j) acc[gt][j] = 0.f;

    #pragma unroll
    for (int i = 0; i < 5; ++i) {
        const int k8 = k8beg + i;
        const float4 wa = *(const float4*)&w2s[k8 * 8];
        const float4 wb = *(const float4*)&w2s[k8 * 8 + 4];
        float f[4][8];
        #pragma unroll
        for (int j = 0; j < 4; ++j) {
            const u16x8 hv = *(const u16x8*)(lpb + ((size_t)k8 * NR + 64 * j) * 8);
            #pragma unroll
            for (int e = 0; e < 8; ++e) f[j][e] = bf2f(hv[e]);
            q[j] = fmaf(wa.x, f[j][0], q[j]); q[j] = fmaf(wa.y, f[j][1], q[j]);
            q[j] = fmaf(wa.z, f[j][2], q[j]); q[j] = fmaf(wa.w, f[j][3], q[j]);
            q[j] = fmaf(wb.x, f[j][4], q[j]); q[j] = fmaf(wb.y, f[j][5], q[j]);
            q[j] = fmaf(wb.z, f[j][6], q[j]); q[j] = fmaf(wb.w, f[j][7], q[j]);
        }
        #pragma unroll
        for (int gt = 0; gt < 8; ++gt) {
            const float4 ga = *(const float4*)&gbs[gt][k8 * 8];
            const float4 gb = *(const float4*)&gbs[gt][k8 * 8 + 4];
            #pragma unroll
            for (int j = 0; j < 4; ++j) {
                acc[gt][j] = fmaf(fabsf(ga.x + f[j][0]), wa.x, acc[gt][j]);
                acc[gt][j] = fmaf(fabsf(ga.y + f[j][1]), wa.y, acc[gt][j]);
                acc[gt][j] = fmaf(fabsf(ga.z + f[j][2]), wa.z, acc[gt][j]);
                acc[gt][j] = fmaf(fabsf(ga.w + f[j][3]), wa.w, acc[gt][j]);
                acc[gt][j] = fmaf(fabsf(gb.x + f[j][4]), wb.x, acc[gt][j]);
                acc[gt][j] = fmaf(fabsf(gb.y + f[j][5]), wb.y, acc[gt][j]);
                acc[gt][j] = fmaf(fabsf(gb.z + f[j][6]), wb.z, acc[gt][j]);
                acc[gt][j] = fmaf(fabsf(gb.w + f[j][7]), wb.w, acc[gt][j]);
            }
        }
    }

    #pragma unroll
    for (int j = 0; j < 4; ++j) {
        *(float4*)&pacc[kh][lh + 64 * j][0] =
            make_float4(acc[0][j] + q[j], acc[1][j] + q[j],
                        acc[2][j] + q[j], acc[3][j] + q[j]);
        *(float4*)&pacc[kh][lh + 64 * j][4] =
            make_float4(acc[4][j] + q[j], acc[5][j] + q[j],
                        acc[6][j] + q[j], acc[7][j] + q[j]);
    }
    __syncthreads();   // pacc + sC ready

    // combine: thread tid<256 = l; s[gt] = sC[gt] + sum_kh pacc[kh][l][gt]
    if (tid < 256) {
        float s[8];
        #pragma unroll
        for (int gt = 0; gt < 8; ++gt) s[gt] = sC[gt];
        #pragma unroll
        for (int k = 0; k < 8; ++k) {
            const float4 p0 = *(const float4*)&pacc[k][tid][0];
            const float4 p1 = *(const float4*)&pacc[k][tid][4];
            s[0] += p0.x; s[1] += p0.y; s[2] += p0.z; s[3] += p0.w;
            s[4] += p1.x; s[5] += p1.y; s[6] += p1.z; s[7] += p1.w;
        }
        const int wid = tid >> 6;
        #pragma unroll
        for (int gt = 0; gt < 8; ++gt) {
            float v = __expf(softplus_f(s[gt] + b2v));
            #pragma unroll
            for (int o = 32; o > 0; o >>= 1) v += __shfl_xor(v, o);
            if ((tid & 63) == 0) red[wid][gt] = v;
        }
    }
    __syncthreads();
    if (tid == 0) {
        #pragma unroll
        for (int gt = 0; gt < 8; ++gt)
            negE[bid * 8 + gt] = red[0][gt] + red[1][gt] + red[2][gt] + red[3][gt];
    }

    // ---- positive term: wave kh handles row bid*8 + kh ----
    {
        const int row = bid * 8 + kh;
        const float4* ra = (const float4*)(P0a + (size_t)row * GSTR);
        const float4* rb = (const float4*)(P0b + (size_t)row * GSTR);
        float d = 0.f;
        #pragma unroll
        for (int h = 0; h < 2; ++h) {
            const int k4 = lh + 64 * h;
            if (k4 < 75) {
                const float4 aa = ra[k4], bb4 = rb[k4];
                const float4 bb = *(const float4*)(b1 + k4 * 4);
                const float4 wv = *(const float4*)(W2 + k4 * 4);
                d += fmaxf(aa.x + bb4.x + bb.x, 0.f) * wv.x
                   + fmaxf(aa.y + bb4.y + bb.y, 0.f) * wv.y
                   + fmaxf(aa.z + bb4.z + bb.z, 0.f) * wv.z
                   + fmaxf(aa.w + bb4.w + bb.w, 0.f) * wv.w;
            }
        }
        #pragma unroll
        for (int o = 32; o > 0; o >>= 1) d += __shfl_xor(d, o);
        if (lh == 0) redp[kh] = softplus_f(d + b2v);
    }
    __syncthreads();

    // ---- last-block finalize (device-scope ticket over 256 blocks) ----
    if (tid == 0) {
        posP[bid] = redp[0] + redp[1] + redp[2] + redp[3]
                  + redp[4] + redp[5] + redp[6] + redp[7];
        __threadfence();
        const unsigned t = atomicAdd(counter, 1u);
        sh_last = (t == NNEG - 1) ? 1 : 0;
    }
    __syncthreads();
    if (sh_last) {
        __threadfence();
        const volatile float* ne = (const volatile float*)negE;
        const volatile float* pp = (const volatile float*)posP;
        float v = 0.f;
        for (int i = tid; i < 2048; i += 512)
            v += __logf(ne[i]);
        if (tid < NNEG) v -= pp[tid];
        #pragma unroll
        for (int o = 32; o > 0; o >>= 1) v += __shfl_xor(v, o);
        if (lh == 0) redp[kh] = v;
        __syncthreads();
        if (tid == 0)
            out[0] = (redp[0] + redp[1] + redp[2] + redp[3]
                    + redp[4] + redp[5] + redp[6] + redp[7]) * (1.f / 2048.f);
    }
}

extern "C" void kernel_launch(void* const* d_in, const int* in_sizes, int n_in,
                              void* d_out, int out_size, void* d_ws, size_t ws_size,
                              hipStream_t stream)
{
    const float* pl = (const float*)d_in[0];
    const float* pg = (const float*)d_in[1];
    const float* nl = (const float*)d_in[2];
    const float* ng = (const float*)d_in[3];
    const float* W1 = (const float*)d_in[4];
    const float* b1 = (const float*)d_in[5];
    const float* W2 = (const float*)d_in[6];
    const float* b2 = (const float*)d_in[7];

    char* ws = (char*)d_ws;
    unsigned short* Wt   = (unsigned short*)(ws);                 // 640 KB
    unsigned short* LP4h = (unsigned short*)(ws + (1u << 20));    // 40*2048*8*2B = 1.31 MB
    unsigned short* GPBh = (unsigned short*)(ws + (3u << 20));    // 2048*304*2B = 1.22 MB
    float* P0a  = (float*)(ws + (5u << 20));                      // 2.49 MB
    float* P0b  = (float*)(ws + (8u << 20));                      // 2.49 MB
    float* negE = (float*)(ws + (11u << 20));                     // 2048 f
    float* posP = negE + 2048;                                    // 256 f
    unsigned int* counter = (unsigned int*)(ws + (11u << 20) + 65536);
    float* out  = (float*)d_out;

    hipLaunchKernelGGL(wconvert, dim3(320), dim3(256), 0, stream,
                       W1, Wt, counter);
    hipLaunchKernelGGL(mfma_gemm, dim3(NR / 32, NPAD / 32, 4), dim3(64), 0, stream,
                       nl, ng, pl, pg, Wt, b1, LP4h, GPBh, P0a, P0b);
    hipLaunchKernelGGL(negpos, dim3(NNEG), dim3(512), 0, stream,
                       LP4h, GPBh, P0a, P0b, b1, W2, b2, negE, posP, counter, out);
}